// Round 1
// 256.966 us; speedup vs baseline: 1.0447x; 1.0447x over previous
//
#include <hip/hip_runtime.h>
#include <hip/hip_bf16.h>
#include <math.h>

#define N_TOK 16384
#define DIM   2048
#define NE    64
#define TOPK  9

#define ROWS     32            // rows per block
#define DC       64            // k-elements per chunk
#define NCHUNK   (DIM / DC)    // 32
#define NTHREADS 256           // 4 waves
#define NBUF     4             // x-stage ring depth (prefetch depth 3)

typedef short  short8  __attribute__((ext_vector_type(8)));
typedef float  float4_ __attribute__((ext_vector_type(4)));
typedef unsigned short ushort_t;

__device__ __forceinline__ void async16(const void* g, void* l) {
    __builtin_amdgcn_global_load_lds(
        (const __attribute__((address_space(1))) void*)g,
        (__attribute__((address_space(3))) void*)l, 16, 0, 0);
}

__device__ __forceinline__ unsigned pk2(float a, float b) {
    float2 f; f.x = a; f.y = b;
    __hip_bfloat162 h = __float22bfloat162_rn(f);   // low16 = bf16(a)
    unsigned u;
    __builtin_memcpy(&u, &h, 4);
    return u;
}

// 8 fp32 -> bf16 hi frag + bf16 lo frag (2-term split)
__device__ __forceinline__ void cvt8(const float4_ va, const float4_ vb,
                                     short8* h, short8* l) {
    union { short8 s; unsigned u[4]; } H, L;
    const float f[8] = {va[0], va[1], va[2], va[3], vb[0], vb[1], vb[2], vb[3]};
#pragma unroll
    for (int i = 0; i < 4; ++i) {
        const float a = f[2 * i], b = f[2 * i + 1];
        const unsigned p = pk2(a, b);
        H.u[i] = p;
        const float ha = __uint_as_float(p << 16);
        const float hb = __uint_as_float(p & 0xffff0000u);
        L.u[i] = pk2(a - ha, b - hb);
    }
    *h = H.s; *l = L.s;
}

__device__ __forceinline__ float wave_max64(float v) {
#pragma unroll
    for (int off = 32; off > 0; off >>= 1)
        v = fmaxf(v, __shfl_xor(v, off, 64));
    return v;
}
__device__ __forceinline__ float wave_sum64(float v) {
#pragma unroll
    for (int off = 32; off > 0; off >>= 1)
        v += __shfl_xor(v, off, 64);
    return v;
}

// ---- prep: Wr|Wn (fp32, D x 64 each) -> B-fragment-ordered bf16 hi/lo ----
// slot s=(kcg*8+ct)*2+t holds 512 bf16: elem l*8+j = B[k=kcg*32+(l>>4)*8+j][n=ct*16+(l&15)]
__global__ __launch_bounds__(256)
void prep_w(const float* __restrict__ Wr, const float* __restrict__ Wn,
            ushort_t* __restrict__ wsW)
{
    const int gid = blockIdx.x * 256 + threadIdx.x;   // [0, 64*8*64)
    const int l   = gid & 63;
    const int ct  = (gid >> 6) & 7;
    const int kcg = gid >> 9;                         // 0..63
    const int n   = ct * 16 + (l & 15);
    const int k0  = kcg * 32 + (l >> 4) * 8;
    const float* src = (n < NE) ? (Wr + n) : (Wn + (n - NE));
    union { short8 s; ushort_t us[8]; } H, L;
#pragma unroll
    for (int j = 0; j < 8; ++j) {
        const float v = src[(size_t)(k0 + j) * NE];
        const unsigned uv = __float_as_uint(v);
        const unsigned hb = (uv + 0x7fffu + ((uv >> 16) & 1u)) & 0xffff0000u;
        const float lo = v - __uint_as_float(hb);
        const unsigned ul = __float_as_uint(lo);
        H.us[j] = (ushort_t)(hb >> 16);
        L.us[j] = (ushort_t)((ul + 0x7fffu + ((ul >> 16) & 1u)) >> 16);
    }
    const size_t s0 = (size_t)(kcg * 8 + ct) * 2;     // slot pair index
    *(short8*)(wsW + s0 * 512 + l * 8)         = H.s;
    *(short8*)(wsW + (s0 + 1) * 512 + l * 8)   = L.s;
}

// B fragments for one chunk, double-buffered in registers across chunks.
struct BFrag { short8 h[2][2]; short8 l[2][2]; };

__device__ __forceinline__ void load_b(const char* __restrict__ wsB,
                                       int ch, int w, int lane, BFrag& b) {
#pragma unroll
    for (int kc = 0; kc < 2; ++kc)
#pragma unroll
        for (int cc = 0; cc < 2; ++cc) {
            const size_t off = (size_t)(((ch * 2 + kc) * 8) + 2 * w + cc) * 2048
                             + (size_t)lane * 16;
            b.h[kc][cc] = *(const short8*)(wsB + off);
            b.l[kc][cc] = *(const short8*)(wsB + off + 1024);
        }
}

__device__ __forceinline__ void mfma_chunk(const float* __restrict__ xb,
                                           const int (&aoff)[2][2],
                                           const BFrag& b,
                                           float4_ (&acc)[2][2]) {
#pragma unroll
    for (int kc = 0; kc < 2; ++kc)
#pragma unroll
        for (int rt = 0; rt < 2; ++rt) {
            const float4_ va = *(const float4_*)(xb + rt * 1024 + aoff[kc][0]);
            const float4_ vb = *(const float4_*)(xb + rt * 1024 + aoff[kc][1]);
            short8 ah, al;
            cvt8(va, vb, &ah, &al);
#pragma unroll
            for (int cc = 0; cc < 2; ++cc) {
                acc[rt][cc] = __builtin_amdgcn_mfma_f32_16x16x32_bf16(ah, b.h[kc][cc], acc[rt][cc], 0, 0, 0);
                acc[rt][cc] = __builtin_amdgcn_mfma_f32_16x16x32_bf16(al, b.h[kc][cc], acc[rt][cc], 0, 0, 0);
                acc[rt][cc] = __builtin_amdgcn_mfma_f32_16x16x32_bf16(ah, b.l[kc][cc], acc[rt][cc], 0, 0, 0);
            }
        }
}

__global__ __launch_bounds__(NTHREADS, 2)
void moe_main(const float* __restrict__ x,
              const float* __restrict__ br,
              const float* __restrict__ bn,
              const float* __restrict__ noise_eps,
              const float* __restrict__ gumbel,
              const ushort_t* __restrict__ wsW,
              float* __restrict__ out)
{
    // x stage ring: 4 x 2048 floats (32 KB); epilogue reuses [0..4159]
    __shared__ __align__(16) float smem[NBUF * 2048];

    const int t    = threadIdx.x;
    const int lane = t & 63;
    const int w    = t >> 6;          // wave 0..3, owns col-tiles {2w, 2w+1}
    const int c4   = lane & 15;
    const int q    = lane >> 4;
    const int row0 = blockIdx.x * ROWS;

    // x staging: 8 issues per chunk (wave w does i=2w,2w+1); issue i covers rows 4i..4i+3
    // lane l -> row 4i+(l>>4); LDS granule pos p=l&15 holds global granule gk=p^(row&15)
    const float* gxb[2];
    int lxo[2];
#pragma unroll
    for (int ii = 0; ii < 2; ++ii) {
        const int i  = 2 * w + ii;
        const int r  = 4 * i + q;
        const int gk = c4 ^ (r & 15);
        gxb[ii] = x + (size_t)(row0 + r) * DIM + gk * 4;  // chunk-0 base
        lxo[ii] = i * 256;            // float offset within a stage buffer
    }

    // A-read offsets (chunk-invariant): row m=rt*16+c4, granules (kc*8+q*2)^c4, +1^c4
    int aoff[2][2];
#pragma unroll
    for (int kc = 0; kc < 2; ++kc) {
        const int g0 = kc * 8 + q * 2;
        aoff[kc][0] = c4 * 64 + ((g0 ^ c4) * 4);
        aoff[kc][1] = c4 * 64 + (((g0 + 1) ^ c4) * 4);
    }

    float4_ acc[2][2];
#pragma unroll
    for (int rt = 0; rt < 2; ++rt)
#pragma unroll
        for (int cc = 0; cc < 2; ++cc)
            acc[rt][cc] = (float4_)(0.f);

    const char* wsB = (const char*)wsW;

    // ---- prologue: stage x chunks 0..2 (depth 3), B(0) into regs ----
#pragma unroll
    for (int p = 0; p < NBUF - 1; ++p)
#pragma unroll
        for (int ii = 0; ii < 2; ++ii)
            async16(gxb[ii] + p * DC, &smem[p * 2048 + lxo[ii]]);

    BFrag bA, bB;
    load_b(wsB, 0, w, lane, bA);

    // Main loop, unrolled by 2 for the B register double-buffer.
    // Per step: wait own vmcnt(12) [steady pending = S(ch+1):2 + S(ch+2):2 + B(ch):8],
    // raw barrier (no vmcnt(0) drain), issue B(ch+1) then S(ch+3), compute chunk ch.
#pragma unroll 1
    for (int ch = 0; ch < NCHUNK; ch += 2) {
        // ---- even step: use bA, prefetch bB ----
        asm volatile("s_waitcnt vmcnt(12)" ::: "memory");
        __builtin_amdgcn_s_barrier();
        asm volatile("" ::: "memory");
        load_b(wsB, (ch + 1 < NCHUNK) ? ch + 1 : NCHUNK - 1, w, lane, bB);
        if (ch + NBUF - 1 < NCHUNK) {
#pragma unroll
            for (int ii = 0; ii < 2; ++ii)
                async16(gxb[ii] + (ch + NBUF - 1) * DC,
                        &smem[((ch + NBUF - 1) & (NBUF - 1)) * 2048 + lxo[ii]]);
        }
        __builtin_amdgcn_sched_barrier(0);   // pin load-issues above compute
        mfma_chunk(&smem[(ch & (NBUF - 1)) * 2048], aoff, bA, acc);

        // ---- odd step: use bB, prefetch bA ----
        asm volatile("s_waitcnt vmcnt(12)" ::: "memory");
        __builtin_amdgcn_s_barrier();
        asm volatile("" ::: "memory");
        load_b(wsB, (ch + 2 < NCHUNK) ? ch + 2 : NCHUNK - 1, w, lane, bA);
        if (ch + NBUF < NCHUNK) {
#pragma unroll
            for (int ii = 0; ii < 2; ++ii)
                async16(gxb[ii] + (ch + NBUF) * DC,
                        &smem[((ch + NBUF) & (NBUF - 1)) * 2048 + lxo[ii]]);
        }
        __builtin_amdgcn_sched_barrier(0);
        mfma_chunk(&smem[((ch + 1) & (NBUF - 1)) * 2048], aoff, bB, acc);
    }

    // ---- epilogue: transpose C tiles through LDS, then per-row wave ops ----
    __syncthreads();                   // full drain (incl. dangling tail B loads)
    float* rawS = &smem[0];            // 32 x 65 (padded)
    float* noiS = &smem[2080];         // 32 x 65
#pragma unroll
    for (int rt = 0; rt < 2; ++rt)
#pragma unroll
        for (int cc = 0; cc < 2; ++cc) {
            const int colg = (2 * w + cc) * 16 + c4;   // 0..127; <64 raw else noise
            float* basep = (colg < NE) ? rawS : noiS;
            const int col = colg & 63;
#pragma unroll
            for (int v = 0; v < 4; ++v) {
                const int row = rt * 16 + q * 4 + v;   // C/D: col=lane&15, row=quad*4+reg
                basep[row * 65 + col] = acc[rt][cc][v];
            }
        }
    __syncthreads();

    const float br_l = br[lane];
    const float bn_l = bn[lane];
    float imp_acc = 0.f, load_acc = 0.f;
    float* out_em   = out;
    float* out_rp   = out + (size_t)N_TOK * NE;
    float* out_imp  = out + (size_t)2 * N_TOK * NE;
    float* out_load = out_imp + NE;

#pragma unroll 1
    for (int r = 0; r < 8; ++r) {
        const int lrow = w * 8 + r;
        const int row  = row0 + lrow;
        const float raw = rawS[lrow * 65 + lane] + br_l;
        const float nl  = noiS[lrow * 65 + lane] + bn_l;
        const float sd = fmaxf(nl, 0.f) + log1pf(expf(-fabsf(nl))) + 0.01f;
        const float epsv = noise_eps[(size_t)row * NE + lane];
        const float gum  = gumbel  [(size_t)row * NE + lane];
        const float noisy = fmaf(epsv, sd, raw);

        float cur = noisy;
        float thr = 0.f, m0 = 0.f;
#pragma unroll 1
        for (int k = 0; k < TOPK; ++k) {
            const float m = wave_max64(cur);
            if (k == 0) m0 = m;
            thr = m;
            const unsigned long long bm = __ballot(cur == m);
            const int first = __ffsll(bm) - 1;
            if (lane == first) cur = -INFINITY;
        }
        const float hard = (noisy >= thr) ? 1.f : 0.f;

        const float g  = noisy + gum;
        const float eg = expf(g - wave_max64(g));
        const float ms = eg / wave_sum64(eg);
        const float em = (hard - ms) + ms;

        const float en = expf(noisy - m0);
        const float rp = en / wave_sum64(en);

        const float er = expf(raw - wave_max64(raw));
        imp_acc += er / wave_sum64(er);

        const float z = (thr - raw) / sd;
        load_acc += 0.5f * erfcf(z * 45.254833995939045f);

        out_em[(size_t)row * NE + lane] = em;
        out_rp[(size_t)row * NE + lane] = rp;
    }

    __syncthreads();                   // rawS/noiS reads done; reuse for reduction
    smem[w * 64 + lane]       = imp_acc;
    smem[256 + w * 64 + lane] = load_acc;
    __syncthreads();
    if (w == 0) {
        const float s1 = smem[lane] + smem[64 + lane] + smem[128 + lane] + smem[192 + lane];
        const float s2 = smem[256 + lane] + smem[320 + lane] + smem[384 + lane] + smem[448 + lane];
        atomicAdd(&out_imp[lane], s1);
        atomicAdd(&out_load[lane], s2);
    }
}

extern "C" void kernel_launch(void* const* d_in, const int* in_sizes, int n_in,
                              void* d_out, int out_size, void* d_ws, size_t ws_size,
                              hipStream_t stream)
{
    const float* x         = (const float*)d_in[0];
    const float* Wr        = (const float*)d_in[1];
    const float* br        = (const float*)d_in[2];
    const float* Wn        = (const float*)d_in[3];
    const float* bn        = (const float*)d_in[4];
    const float* noise_eps = (const float*)d_in[5];
    const float* gumbel    = (const float*)d_in[6];
    float* out = (float*)d_out;
    ushort_t* wsW = (ushort_t*)d_ws;   // 1 MB (64*8*2 slots x 1 KB)

    (void)hipMemsetAsync((char*)d_out + (size_t)2 * N_TOK * NE * sizeof(float), 0,
                         2 * NE * sizeof(float), stream);
    prep_w<<<128, 256, 0, stream>>>(Wr, Wn, wsW);
    moe_main<<<N_TOK / ROWS, NTHREADS, 0, stream>>>(
        x, br, bn, noise_eps, gumbel, wsW, out);
}